// Round 3
// baseline (507.944 us; speedup 1.0000x reference)
//
#include <hip/hip_runtime.h>
#include <math.h>

// Problem constants (GumbelVectorQuantizer): B=16,T=2048,D=512,M=1024
#define NTOT 32768   // B*T
#define DDIM 512
#define MDIM 1024
#define BN   32      // rows per block
#define QOFF 16777216  // quantized element count (output scalars follow)

typedef _Float16 f16x8 __attribute__((ext_vector_type(8)));
typedef float    f32x4 __attribute__((ext_vector_type(4)));

// ---------------------------------------------------------------------------
// esq[m] = sum_d e[m][d]^2   (tree-reduced: accuracy matters for argmax)
__global__ __launch_bounds__(256) void esq_kernel(const float* __restrict__ e,
                                                  float* __restrict__ esq) {
  const int w = threadIdx.x >> 6, lane = threadIdx.x & 63;
  const int m = blockIdx.x * 4 + w;
  const float4* row = (const float4*)(e + (size_t)m * DDIM);
  const float4 a = row[lane * 2];
  const float4 b = row[lane * 2 + 1];
  float s = ((a.x * a.x + a.y * a.y) + (a.z * a.z + a.w * a.w)) +
            ((b.x * b.x + b.y * b.y) + (b.z * b.z + b.w * b.w));
#pragma unroll
  for (int off = 32; off; off >>= 1) s += __shfl_xor(s, off);
  if (lane == 0) esq[m] = s;
}

// ---------------------------------------------------------------------------
// Pre-swizzle E into MFMA B-fragment order, fp16 hi/lo split.
// Fragment id F = ctg*16 + ks. Lane l elem j holds
// B[k = ks*32 + (l>>4)*8 + j][col = ctg*16 + (l&15)] = E[col][k].
__global__ __launch_bounds__(256) void e_to_frag(const float* __restrict__ e,
                                                 _Float16* __restrict__ hi,
                                                 _Float16* __restrict__ lo) {
  const int tid = blockIdx.x * 256 + threadIdx.x;   // 65536 threads
  const int lane = tid & 63;
  const int F = tid >> 6;
  const int ctg = F >> 4, ks = F & 15;
  const int m = ctg * 16 + (lane & 15);
  const int k0 = ks * 32 + (lane >> 4) * 8;
  const float* src = e + (size_t)m * DDIM + k0;
  const float4 a = *(const float4*)src;
  const float4 b = *(const float4*)(src + 4);
  const float v0 = a.x, v1 = a.y, v2 = a.z, v3 = a.w;
  const float v4 = b.x, v5 = b.y, v6 = b.z, v7 = b.w;
  f16x8 vh, vl;
  vh[0] = (_Float16)v0; vl[0] = (_Float16)(v0 - (float)vh[0]);
  vh[1] = (_Float16)v1; vl[1] = (_Float16)(v1 - (float)vh[1]);
  vh[2] = (_Float16)v2; vl[2] = (_Float16)(v2 - (float)vh[2]);
  vh[3] = (_Float16)v3; vl[3] = (_Float16)(v3 - (float)vh[3]);
  vh[4] = (_Float16)v4; vl[4] = (_Float16)(v4 - (float)vh[4]);
  vh[5] = (_Float16)v5; vl[5] = (_Float16)(v5 - (float)vh[5]);
  vh[6] = (_Float16)v6; vl[6] = (_Float16)(v6 - (float)vh[6]);
  vh[7] = (_Float16)v7; vl[7] = (_Float16)(v7 - (float)vh[7]);
  *(f16x8*)(hi + (size_t)tid * 8) = vh;
  *(f16x8*)(lo + (size_t)tid * 8) = vl;
}

// ---------------------------------------------------------------------------
#define AMAX(V, MM)                                                            \
  { const float v_ = (V); const int m_ = (MM);                                 \
    if (v_ > bv || (v_ == bv && m_ < bi)) { bv = v_; bi = m_; } }
#define GMAX(V, MM)                                                            \
  { const float v_ = (V); const int m_ = (MM);                                 \
    if (v_ > gv || (v_ == gv && m_ < gi)) { gv = v_; gi = m_; } }

// ---- software-pipelined GEMM helpers (all indices compile-time static) -----
// Load half-ct group H (ct = H*4..H*4+3) of K-step KS into (BH,BL).
#define LOADBH(KS, H, BH, BL)                                                  \
  _Pragma("unroll") for (int c_ = 0; c_ < 4; ++c_) {                           \
    const size_t foff_ =                                                       \
        (((size_t)(w8 + (H) * 4 + c_) * 16 + (KS)) * 64 + lane) * 8;           \
    BH[c_] = *(const f16x8*)(ehi + foff_);                                     \
    BL[c_] = *(const f16x8*)(elo + foff_);                                     \
  }

#define LOADA(KS, AR)                                                          \
  {                                                                            \
    const int k0_ = (KS) * 32 + lg * 8;                                        \
    AR[0] = *(const float4*)(xr0 + k0_);                                       \
    AR[1] = *(const float4*)(xr0 + k0_ + 4);                                   \
    AR[2] = *(const float4*)(xr1 + k0_);                                       \
    AR[3] = *(const float4*)(xr1 + k0_ + 4);                                   \
  }

#define CVT1(V, RT, J)                                                         \
  Ah[RT][J] = (_Float16)(V);                                                   \
  Al[RT][J] = (_Float16)((V) - (float)Ah[RT][J]);

#define CVT(AR)                                                                \
  CVT1(AR[0].x, 0, 0) CVT1(AR[0].y, 0, 1) CVT1(AR[0].z, 0, 2)                  \
  CVT1(AR[0].w, 0, 3) CVT1(AR[1].x, 0, 4) CVT1(AR[1].y, 0, 5)                  \
  CVT1(AR[1].z, 0, 6) CVT1(AR[1].w, 0, 7)                                      \
  CVT1(AR[2].x, 1, 0) CVT1(AR[2].y, 1, 1) CVT1(AR[2].z, 1, 2)                  \
  CVT1(AR[2].w, 1, 3) CVT1(AR[3].x, 1, 4) CVT1(AR[3].y, 1, 5)                  \
  CVT1(AR[3].z, 1, 6) CVT1(AR[3].w, 1, 7)

// term-major MFMA over a 4-ct half (CTB = 0 or 4): same-acc ops spaced 8 apart
#define MFMAH(BH, BL, CTB)                                                     \
  _Pragma("unroll") for (int c_ = 0; c_ < 4; ++c_)                             \
  _Pragma("unroll") for (int rt_ = 0; rt_ < 2; ++rt_)                          \
      acc[rt_][(CTB) + c_] = __builtin_amdgcn_mfma_f32_16x16x32_f16(           \
          Ah[rt_], BH[c_], acc[rt_][(CTB) + c_], 0, 0, 0);                     \
  _Pragma("unroll") for (int c_ = 0; c_ < 4; ++c_)                             \
  _Pragma("unroll") for (int rt_ = 0; rt_ < 2; ++rt_)                          \
      acc[rt_][(CTB) + c_] = __builtin_amdgcn_mfma_f32_16x16x32_f16(           \
          Al[rt_], BH[c_], acc[rt_][(CTB) + c_], 0, 0, 0);                     \
  _Pragma("unroll") for (int c_ = 0; c_ < 4; ++c_)                             \
  _Pragma("unroll") for (int rt_ = 0; rt_ < 2; ++rt_)                          \
      acc[rt_][(CTB) + c_] = __builtin_amdgcn_mfma_f32_16x16x32_f16(           \
          Ah[rt_], BL[c_], acc[rt_][(CTB) + c_], 0, 0, 0);

// One K-step: prefetch cur's half-1 + next's half-0/A while MFMAing.
#define KSBODY(KS, ARc, ARn, PREF)                                             \
  LOADBH(KS, 1, B1h, B1l)                                                      \
  CVT(ARc)                                                                     \
  MFMAH(B0h, B0l, 0)                                                           \
  if (PREF) { LOADBH((KS) + 1, 0, B0h, B0l) LOADA((KS) + 1, ARn) }             \
  MFMAH(B1h, B1l, 4)

// Main fused kernel: G = X.E^T via fp16-split MFMA (3 mfma per tile), then
// per-row argmax / softmax->avg_probs / gumbel argmax -> gather + SSE.
__global__ __launch_bounds__(512, 2)
void vq_main(const float* __restrict__ x, const float* __restrict__ emb,
             const _Float16* __restrict__ ehi, const _Float16* __restrict__ elo,
             const float* __restrict__ gum, const float* __restrict__ esq,
             float* __restrict__ out, float* __restrict__ avg_acc,
             int* __restrict__ counts, float* __restrict__ sse) {
  __shared__ float Lds[16 * 1028];   // one 16-row G slab, padded (+4) stride
  __shared__ float esq_s[MDIM];
  __shared__ float avg_s[MDIM];

  const int t = threadIdx.x;
  const int w = t >> 6;
  const int w8 = w * 8;
  const int lane = t & 63;
  const int l15 = lane & 15;
  const int lg = lane >> 4;
  const int co = lane << 2;
  const int n0 = blockIdx.x * BN;

  avg_s[t] = 0.f; avg_s[t + 512] = 0.f;
  esq_s[t] = esq[t]; esq_s[t + 512] = esq[t + 512];

  f32x4 acc[2][8];
#pragma unroll
  for (int rt = 0; rt < 2; ++rt)
#pragma unroll
    for (int ct = 0; ct < 8; ++ct) acc[rt][ct] = (f32x4){0.f, 0.f, 0.f, 0.f};

  const float* xr0 = x + (size_t)(n0 + l15) * DDIM;
  const float* xr1 = xr0 + (size_t)16 * DDIM;

  // register double-buffers for the pipeline
  f16x8 B0h[4], B0l[4], B1h[4], B1l[4];
  float4 Ar0[4], Ar1[4];
  f16x8 Ah[2], Al[2];

  // prologue
  LOADBH(0, 0, B0h, B0l)
  LOADA(0, Ar0)

  // 16 K-steps, fully unrolled, alternating A buffers
  KSBODY(0,  Ar0, Ar1, 1)
  KSBODY(1,  Ar1, Ar0, 1)
  KSBODY(2,  Ar0, Ar1, 1)
  KSBODY(3,  Ar1, Ar0, 1)
  KSBODY(4,  Ar0, Ar1, 1)
  KSBODY(5,  Ar1, Ar0, 1)
  KSBODY(6,  Ar0, Ar1, 1)
  KSBODY(7,  Ar1, Ar0, 1)
  KSBODY(8,  Ar0, Ar1, 1)
  KSBODY(9,  Ar1, Ar0, 1)
  KSBODY(10, Ar0, Ar1, 1)
  KSBODY(11, Ar1, Ar0, 1)
  KSBODY(12, Ar0, Ar1, 1)
  KSBODY(13, Ar1, Ar0, 1)
  KSBODY(14, Ar0, Ar1, 1)
  KSBODY(15, Ar1, Ar0, 0)

  // ----- epilogue: two passes of 16 rows through LDS, per-row reductions ----
  __syncthreads();  // esq_s/avg_s ready
  const float4 es0 = *(const float4*)&esq_s[co];
  const float4 es1 = *(const float4*)&esq_s[co + 256];
  const float4 es2 = *(const float4*)&esq_s[co + 512];
  const float4 es3 = *(const float4*)&esq_s[co + 768];
  float4 cav0 = make_float4(0.f, 0.f, 0.f, 0.f);
  float4 cav1 = make_float4(0.f, 0.f, 0.f, 0.f);
  float4 cav2 = make_float4(0.f, 0.f, 0.f, 0.f);
  float4 cav3 = make_float4(0.f, 0.f, 0.f, 0.f);

#pragma unroll
  for (int pass = 0; pass < 2; ++pass) {
    // scatter this pass's row-tile to LDS: C/D layout row=(lg*4+reg)
#pragma unroll
    for (int ct = 0; ct < 8; ++ct) {
      const int col = w * 128 + ct * 16 + l15;
#pragma unroll
      for (int rg = 0; rg < 4; ++rg)
        Lds[(lg * 4 + rg) * 1028 + col] = acc[pass][ct][rg];
    }
    __syncthreads();

#pragma unroll
    for (int i = 0; i < 2; ++i) {
      const int lr = 2 * w + i;
      const int n = n0 + pass * 16 + lr;
      const float* Lr = &Lds[lr * 1028];
      // issue gumbel loads early so latency hides under argmax/softmax
      const float4* grow = (const float4*)(gum + (size_t)n * MDIM);
      const float4 q0 = grow[lane];
      const float4 q1 = grow[lane + 64];
      const float4 q2 = grow[lane + 128];
      const float4 q3 = grow[lane + 192];

      const float4 g0 = *(const float4*)&Lr[co];
      const float4 g1 = *(const float4*)&Lr[co + 256];
      const float4 g2 = *(const float4*)&Lr[co + 512];
      const float4 g3 = *(const float4*)&Lr[co + 768];
      // dmap' (row-shift-invariant part): 10*G - 5*||e||^2
      float4 d0, d1, d2, d3;
      d0.x = 10.f * g0.x - 5.f * es0.x; d0.y = 10.f * g0.y - 5.f * es0.y;
      d0.z = 10.f * g0.z - 5.f * es0.z; d0.w = 10.f * g0.w - 5.f * es0.w;
      d1.x = 10.f * g1.x - 5.f * es1.x; d1.y = 10.f * g1.y - 5.f * es1.y;
      d1.z = 10.f * g1.z - 5.f * es1.z; d1.w = 10.f * g1.w - 5.f * es1.w;
      d2.x = 10.f * g2.x - 5.f * es2.x; d2.y = 10.f * g2.y - 5.f * es2.y;
      d2.z = 10.f * g2.z - 5.f * es2.z; d2.w = 10.f * g2.w - 5.f * es2.w;
      d3.x = 10.f * g3.x - 5.f * es3.x; d3.y = 10.f * g3.y - 5.f * es3.y;
      d3.z = 10.f * g3.z - 5.f * es3.z; d3.w = 10.f * g3.w - 5.f * es3.w;

      // hard argmax (first-index tiebreak)
      float bv = -3.402823466e+38f; int bi = 0;
      AMAX(d0.x, co + 0)   AMAX(d0.y, co + 1)   AMAX(d0.z, co + 2)   AMAX(d0.w, co + 3)
      AMAX(d1.x, co + 256) AMAX(d1.y, co + 257) AMAX(d1.z, co + 258) AMAX(d1.w, co + 259)
      AMAX(d2.x, co + 512) AMAX(d2.y, co + 513) AMAX(d2.z, co + 514) AMAX(d2.w, co + 515)
      AMAX(d3.x, co + 768) AMAX(d3.y, co + 769) AMAX(d3.z, co + 770) AMAX(d3.w, co + 771)
#pragma unroll
      for (int off = 32; off; off >>= 1) {
        const float ov = __shfl_xor(bv, off);
        const int oi = __shfl_xor(bi, off);
        if (ov > bv || (ov == bv && oi < bi)) { bv = ov; bi = oi; }
      }
      if (lane == 0) atomicAdd(&counts[bi], 1);

      // softmax(dmap) -> avg_probs contribution (bv is the row max)
      float4 p0, p1, p2, p3;
      p0.x = __expf(d0.x - bv); p0.y = __expf(d0.y - bv); p0.z = __expf(d0.z - bv); p0.w = __expf(d0.w - bv);
      p1.x = __expf(d1.x - bv); p1.y = __expf(d1.y - bv); p1.z = __expf(d1.z - bv); p1.w = __expf(d1.w - bv);
      p2.x = __expf(d2.x - bv); p2.y = __expf(d2.y - bv); p2.z = __expf(d2.z - bv); p2.w = __expf(d2.w - bv);
      p3.x = __expf(d3.x - bv); p3.y = __expf(d3.y - bv); p3.z = __expf(d3.z - bv); p3.w = __expf(d3.w - bv);
      float ssum = (((p0.x + p0.y) + (p0.z + p0.w)) + ((p1.x + p1.y) + (p1.z + p1.w))) +
                   (((p2.x + p2.y) + (p2.z + p2.w)) + ((p3.x + p3.y) + (p3.z + p3.w)));
#pragma unroll
      for (int off = 32; off; off >>= 1) ssum += __shfl_xor(ssum, off);
      const float inv = 1.0f / ssum;
      cav0.x += p0.x * inv; cav0.y += p0.y * inv; cav0.z += p0.z * inv; cav0.w += p0.w * inv;
      cav1.x += p1.x * inv; cav1.y += p1.y * inv; cav1.z += p1.z * inv; cav1.w += p1.w * inv;
      cav2.x += p2.x * inv; cav2.y += p2.y * inv; cav2.z += p2.z * inv; cav2.w += p2.w * inv;
      cav3.x += p3.x * inv; cav3.y += p3.y * inv; cav3.z += p3.z * inv; cav3.w += p3.w * inv;

      // gumbel path argmax -> quantized index
      float gv = -3.402823466e+38f; int gi = 0;
      GMAX(d0.x + q0.x, co + 0)   GMAX(d0.y + q0.y, co + 1)
      GMAX(d0.z + q0.z, co + 2)   GMAX(d0.w + q0.w, co + 3)
      GMAX(d1.x + q1.x, co + 256) GMAX(d1.y + q1.y, co + 257)
      GMAX(d1.z + q1.z, co + 258) GMAX(d1.w + q1.w, co + 259)
      GMAX(d2.x + q2.x, co + 512) GMAX(d2.y + q2.y, co + 513)
      GMAX(d2.z + q2.z, co + 514) GMAX(d2.w + q2.w, co + 515)
      GMAX(d3.x + q3.x, co + 768) GMAX(d3.y + q3.y, co + 769)
      GMAX(d3.z + q3.z, co + 770) GMAX(d3.w + q3.w, co + 771)
#pragma unroll
      for (int off = 32; off; off >>= 1) {
        const float ov = __shfl_xor(gv, off);
        const int oi = __shfl_xor(gi, off);
        if (ov > gv || (ov == gv && oi < gi)) { gv = ov; gi = oi; }
      }

      // quantized[n] = embedding[gi]; commitment SSE
      const float4* erow = (const float4*)(emb + (size_t)gi * DDIM);
      const float4* xrow = (const float4*)(x + (size_t)n * DDIM);
      float4* orow = (float4*)(out + (size_t)n * DDIM);
      float ss = 0.f;
#pragma unroll
      for (int c2 = 0; c2 < 2; ++c2) {
        const int f = lane + 64 * c2;
        const float4 ev = erow[f];
        const float4 xv = xrow[f];
        orow[f] = ev;
        const float q0_ = xv.x - ev.x, q1_ = xv.y - ev.y;
        const float q2_ = xv.z - ev.z, q3_ = xv.w - ev.w;
        ss += (q0_ * q0_ + q1_ * q1_) + (q2_ * q2_ + q3_ * q3_);
      }
#pragma unroll
      for (int off = 32; off; off >>= 1) ss += __shfl_xor(ss, off);
      if (lane == 0) atomicAdd(sse, ss);
    }
    __syncthreads();  // Lds reused by next pass
  }

  // flush avg_probs contributions: LDS accumulate, then one global atom/elem
  atomicAdd(&avg_s[co + 0], cav0.x);   atomicAdd(&avg_s[co + 1], cav0.y);
  atomicAdd(&avg_s[co + 2], cav0.z);   atomicAdd(&avg_s[co + 3], cav0.w);
  atomicAdd(&avg_s[co + 256], cav1.x); atomicAdd(&avg_s[co + 257], cav1.y);
  atomicAdd(&avg_s[co + 258], cav1.z); atomicAdd(&avg_s[co + 259], cav1.w);
  atomicAdd(&avg_s[co + 512], cav2.x); atomicAdd(&avg_s[co + 513], cav2.y);
  atomicAdd(&avg_s[co + 514], cav2.z); atomicAdd(&avg_s[co + 515], cav2.w);
  atomicAdd(&avg_s[co + 768], cav3.x); atomicAdd(&avg_s[co + 769], cav3.y);
  atomicAdd(&avg_s[co + 770], cav3.z); atomicAdd(&avg_s[co + 771], cav3.w);
  __syncthreads();
  atomicAdd(&avg_acc[t], avg_s[t]);
  atomicAdd(&avg_acc[t + 512], avg_s[t + 512]);
}

// ---------------------------------------------------------------------------
__global__ __launch_bounds__(1024)
void finalize(const float* __restrict__ avg_acc, const int* __restrict__ counts,
              const float* __restrict__ sse, float* __restrict__ out) {
  __shared__ float red[32];
  const int t = threadIdx.x;
  const float invN = 1.f / 32768.f;
  const float p = (float)counts[t] * invN;
  float a = p * log2f(p + 1e-10f);
  const float q = avg_acc[t] * invN;
  float b = q * log2f(q + 1e-10f);
#pragma unroll
  for (int off = 32; off; off >>= 1) {
    a += __shfl_xor(a, off);
    b += __shfl_xor(b, off);
  }
  const int wv = t >> 6, ln = t & 63;
  if (ln == 0) { red[wv] = a; red[wv + 16] = b; }
  __syncthreads();
  if (t == 0) {
    float sa = 0.f, sb = 0.f;
#pragma unroll
    for (int i = 0; i < 16; ++i) { sa += red[i]; sb += red[i + 16]; }
    out[QOFF + 0] = -sa;                                // code_perplexity
    out[QOFF + 1] = -sb;                                // prob_perplexity
    out[QOFF + 2] = sse[0] * (1.f / (32768.f * 512.f)); // commitment_loss
  }
}

// ---------------------------------------------------------------------------
extern "C" void kernel_launch(void* const* d_in, const int* in_sizes, int n_in,
                              void* d_out, int out_size, void* d_ws,
                              size_t ws_size, hipStream_t stream) {
  const float* x = (const float*)d_in[0];
  const float* e = (const float*)d_in[1];
  const float* g = (const float*)d_in[2];
  float* out = (float*)d_out;
  float* ws = (float*)d_ws;
  // ws layout (floats): [0,1024) esq | [1024,2048) avg_acc |
  //   [2048,3072) counts(int) | [3072] sse | [4096, +512K) Ehi/Elo fragments
  float* esq = ws;
  float* avg_acc = ws + 1024;
  int* counts = (int*)(ws + 2048);
  float* sse = ws + 3072;
  _Float16* ehi = (_Float16*)(ws + 4096);        // 1024*512 halves = 1 MB
  _Float16* elo = ehi + (size_t)MDIM * DDIM;     // 1 MB

  // zero the cross-block accumulators (ws is poisoned 0xAA, not re-zeroed)
  hipMemsetAsync(avg_acc, 0, (1024 + 1024 + 1) * sizeof(float), stream);

  e_to_frag<<<256, 256, 0, stream>>>(e, ehi, elo);
  esq_kernel<<<256, 256, 0, stream>>>(e, esq);
  vq_main<<<NTOT / BN, 512, 0, stream>>>(x, e, ehi, elo, g, esq, out, avg_acc,
                                         counts, sse);
  finalize<<<1, 1024, 0, stream>>>(avg_acc, counts, sse, out);
}

// Round 4
// 441.478 us; speedup vs baseline: 1.1506x; 1.1506x over previous
//
#include <hip/hip_runtime.h>
#include <math.h>

// Problem constants (GumbelVectorQuantizer): B=16,T=2048,D=512,M=1024
#define NTOT 32768   // B*T
#define DDIM 512
#define MDIM 1024
#define BN   64      // rows per block
#define QOFF 16777216  // quantized element count (output scalars follow)

typedef _Float16 f16x8 __attribute__((ext_vector_type(8)));
typedef float    f32x4 __attribute__((ext_vector_type(4)));

// async global->LDS (16B per lane, wave-uniform LDS base)
__device__ __forceinline__ void gload_lds16(const void* g, void* l) {
  __builtin_amdgcn_global_load_lds(
      (const __attribute__((address_space(1))) void*)g,
      (__attribute__((address_space(3))) void*)l, 16, 0, 0);
}

// ---------------------------------------------------------------------------
// esq[m] = sum_d e[m][d]^2   (tree-reduced: accuracy matters for argmax)
__global__ __launch_bounds__(256) void esq_kernel(const float* __restrict__ e,
                                                  float* __restrict__ esq) {
  const int w = threadIdx.x >> 6, lane = threadIdx.x & 63;
  const int m = blockIdx.x * 4 + w;
  const float4* row = (const float4*)(e + (size_t)m * DDIM);
  const float4 a = row[lane * 2];
  const float4 b = row[lane * 2 + 1];
  float s = ((a.x * a.x + a.y * a.y) + (a.z * a.z + a.w * a.w)) +
            ((b.x * b.x + b.y * b.y) + (b.z * b.z + b.w * b.w));
#pragma unroll
  for (int off = 32; off; off >>= 1) s += __shfl_xor(s, off);
  if (lane == 0) esq[m] = s;
}

// ---------------------------------------------------------------------------
// Pre-swizzle E into MFMA B-fragment order, fp16 hi/lo split, KS-MAJOR layout:
// flat half index = ((ks*64 + ctg)*64 + lane)*8, so one K-step's slab is a
// contiguous 64 KB chunk (global_load_lds-stageable linearly).
// Lane l elem j holds B[k = ks*32 + (l>>4)*8 + j][col = ctg*16 + (l&15)].
__global__ __launch_bounds__(256) void e_to_frag(const float* __restrict__ e,
                                                 _Float16* __restrict__ hi,
                                                 _Float16* __restrict__ lo) {
  const int tid = blockIdx.x * 256 + threadIdx.x;   // 65536 threads
  const int lane = tid & 63;
  const int F = tid >> 6;          // F = ks*64 + ctg
  const int ctg = F & 63, ks = F >> 6;
  const int m = ctg * 16 + (lane & 15);
  const int k0 = ks * 32 + (lane >> 4) * 8;
  const float* src = e + (size_t)m * DDIM + k0;
  const float4 a = *(const float4*)src;
  const float4 b = *(const float4*)(src + 4);
  const float v0 = a.x, v1 = a.y, v2 = a.z, v3 = a.w;
  const float v4 = b.x, v5 = b.y, v6 = b.z, v7 = b.w;
  f16x8 vh, vl;
  vh[0] = (_Float16)v0; vl[0] = (_Float16)(v0 - (float)vh[0]);
  vh[1] = (_Float16)v1; vl[1] = (_Float16)(v1 - (float)vh[1]);
  vh[2] = (_Float16)v2; vl[2] = (_Float16)(v2 - (float)vh[2]);
  vh[3] = (_Float16)v3; vl[3] = (_Float16)(v3 - (float)vh[3]);
  vh[4] = (_Float16)v4; vl[4] = (_Float16)(v4 - (float)vh[4]);
  vh[5] = (_Float16)v5; vl[5] = (_Float16)(v5 - (float)vh[5]);
  vh[6] = (_Float16)v6; vl[6] = (_Float16)(v6 - (float)vh[6]);
  vh[7] = (_Float16)v7; vl[7] = (_Float16)(v7 - (float)vh[7]);
  *(f16x8*)(hi + (size_t)tid * 8) = vh;
  *(f16x8*)(lo + (size_t)tid * 8) = vl;
}

// ---------------------------------------------------------------------------
#define AMAX(V, MM)                                                            \
  { const float v_ = (V); const int m_ = (MM);                                 \
    if (v_ > bv || (v_ == bv && m_ < bi)) { bv = v_; bi = m_; } }
#define GMAX(V, MM)                                                            \
  { const float v_ = (V); const int m_ = (MM);                                 \
    if (v_ > gv || (v_ == gv && m_ < gi)) { gv = v_; gi = m_; } }

// stage one 64KB slab (global byte base GB) into LDS buffer LB
#define STAGE(GB, LB)                                                          \
  _Pragma("unroll") for (int i_ = 0; i_ < 8; ++i_)                             \
      gload_lds16((const char*)(GB) + stgG + i_ * 8192,                        \
                  (char*)(LB) + wb + i_ * 8192);

// load x K-slice KS and convert to fp16 hi/lo fragments (4 row-tiles)
#define LOADCVT(KS)                                                            \
  _Pragma("unroll") for (int rt_ = 0; rt_ < 4; ++rt_) {                        \
    const float* xr_ = xrb + (size_t)rt_ * (16 * DDIM) + (KS) * 32 + lg8;      \
    const float4 a_ = *(const float4*)xr_;                                     \
    const float4 b_ = *(const float4*)(xr_ + 4);                               \
    Ah[rt_][0] = (_Float16)a_.x; Al[rt_][0] = (_Float16)(a_.x - (float)Ah[rt_][0]); \
    Ah[rt_][1] = (_Float16)a_.y; Al[rt_][1] = (_Float16)(a_.y - (float)Ah[rt_][1]); \
    Ah[rt_][2] = (_Float16)a_.z; Al[rt_][2] = (_Float16)(a_.z - (float)Ah[rt_][2]); \
    Ah[rt_][3] = (_Float16)a_.w; Al[rt_][3] = (_Float16)(a_.w - (float)Ah[rt_][3]); \
    Ah[rt_][4] = (_Float16)b_.x; Al[rt_][4] = (_Float16)(b_.x - (float)Ah[rt_][4]); \
    Ah[rt_][5] = (_Float16)b_.y; Al[rt_][5] = (_Float16)(b_.y - (float)Ah[rt_][5]); \
    Ah[rt_][6] = (_Float16)b_.z; Al[rt_][6] = (_Float16)(b_.z - (float)Ah[rt_][6]); \
    Ah[rt_][7] = (_Float16)b_.w; Al[rt_][7] = (_Float16)(b_.w - (float)Ah[rt_][7]); \
  }

// Main fused kernel: G = X.E^T via fp16-split MFMA with 2-phase LDS pipeline
// (global_load_lds double-buffer), then per-row argmax / softmax->avg_probs /
// gumbel argmax -> gather + SSE.  8 waves; wave owns 64 rows x 128 cols.
__global__ __launch_bounds__(512, 2)
void vq_main(const float* __restrict__ x, const float* __restrict__ emb,
             const _Float16* __restrict__ ehi, const _Float16* __restrict__ elo,
             const float* __restrict__ gum, const float* __restrict__ esq,
             float* __restrict__ out, float* __restrict__ avg_acc,
             int* __restrict__ counts, float* __restrict__ sse) {
  __shared__ __align__(16) char smem[131072];  // 2 x 64KB slab dbuf
  __shared__ float esq_s[MDIM];
  __shared__ float avg_s[MDIM];
  char* bufA = smem;           // hi slabs land here (even phases)
  char* bufB = smem + 65536;   // lo slabs land here (odd phases)

  const int t = threadIdx.x;
  const int w = t >> 6;
  const int w8 = w * 8;
  const int lane = t & 63;
  const int l15 = lane & 15;
  const int lg = lane >> 4;
  const int lg8 = lg * 8;
  const int l16 = lane << 4;
  const int co = lane << 2;
  const int wb = w * 1024;               // wave-uniform LDS byte base
  const int stgG = wb + l16;             // per-lane global byte offset in slab
  const int n0 = blockIdx.x * BN;

  avg_s[t] = 0.f; avg_s[t + 512] = 0.f;
  esq_s[t] = esq[t]; esq_s[t + 512] = esq[t + 512];

  f32x4 acc[4][8];
#pragma unroll
  for (int rt = 0; rt < 4; ++rt)
#pragma unroll
    for (int ct = 0; ct < 8; ++ct) acc[rt][ct] = (f32x4){0.f, 0.f, 0.f, 0.f};

  const float* xrb = x + (size_t)(n0 + l15) * DDIM;
  f16x8 Ah[4], Al[4], Bf[8];

  // prologue: stage hi[0], load+convert A[0]
  STAGE((const char*)ehi, bufA)
  LOADCVT(0)
  __syncthreads();

  for (int ks = 0; ks < 16; ++ks) {
    // ---- phase A: stage lo[ks] -> bufB; compute AhBh + AlBh from bufA ----
    STAGE((const char*)elo + (size_t)ks * 65536, bufB)
#pragma unroll
    for (int c = 0; c < 8; ++c)
      Bf[c] = *(const f16x8*)(bufA + ((w8 + c) << 10) + l16);
#pragma unroll
    for (int c = 0; c < 8; ++c)
#pragma unroll
      for (int rt = 0; rt < 4; ++rt)
        acc[rt][c] = __builtin_amdgcn_mfma_f32_16x16x32_f16(Ah[rt], Bf[c],
                                                            acc[rt][c], 0, 0, 0);
#pragma unroll
    for (int c = 0; c < 8; ++c)
#pragma unroll
      for (int rt = 0; rt < 4; ++rt)
        acc[rt][c] = __builtin_amdgcn_mfma_f32_16x16x32_f16(Al[rt], Bf[c],
                                                            acc[rt][c], 0, 0, 0);
    __syncthreads();  // lo[ks] resident; bufA free for restage

    // ---- phase B: stage hi[ks+1] -> bufA; compute AhBl from bufB ----
    if (ks + 1 < 16) { STAGE((const char*)ehi + (size_t)(ks + 1) * 65536, bufA) }
#pragma unroll
    for (int c = 0; c < 8; ++c)
      Bf[c] = *(const f16x8*)(bufB + ((w8 + c) << 10) + l16);
#pragma unroll
    for (int c = 0; c < 8; ++c)
#pragma unroll
      for (int rt = 0; rt < 4; ++rt)
        acc[rt][c] = __builtin_amdgcn_mfma_f32_16x16x32_f16(Ah[rt], Bf[c],
                                                            acc[rt][c], 0, 0, 0);
    if (ks + 1 < 16) { LOADCVT(ks + 1) }  // after AhBl issued (Ah dead now)
    __syncthreads();  // hi[ks+1] resident; bufB free for restage
  }

  // ----- epilogue: four passes of 16 rows through LDS (aliases stage bufs) --
  float* Lds = (float*)smem;  // 16 x 1028 floats = 65.8 KB
  const float4 es0 = *(const float4*)&esq_s[co];
  const float4 es1 = *(const float4*)&esq_s[co + 256];
  const float4 es2 = *(const float4*)&esq_s[co + 512];
  const float4 es3 = *(const float4*)&esq_s[co + 768];
  float4 cav0 = make_float4(0.f, 0.f, 0.f, 0.f);
  float4 cav1 = make_float4(0.f, 0.f, 0.f, 0.f);
  float4 cav2 = make_float4(0.f, 0.f, 0.f, 0.f);
  float4 cav3 = make_float4(0.f, 0.f, 0.f, 0.f);
  float ss_wave = 0.f;

#pragma unroll
  for (int pass = 0; pass < 4; ++pass) {
    // scatter this pass's row-tile to LDS: C/D layout row=(lg*4+reg)
#pragma unroll
    for (int ct = 0; ct < 8; ++ct) {
      const int col = w * 128 + ct * 16 + l15;
#pragma unroll
      for (int rg = 0; rg < 4; ++rg)
        Lds[(lg * 4 + rg) * 1028 + col] = acc[pass][ct][rg];
    }
    __syncthreads();

#pragma unroll
    for (int i = 0; i < 2; ++i) {
      const int lr = 2 * w + i;
      const int n = n0 + pass * 16 + lr;
      const float* Lr = &Lds[lr * 1028];
      // issue gumbel loads early so latency hides under argmax/softmax
      const float4* grow = (const float4*)(gum + (size_t)n * MDIM);
      const float4 q0 = grow[lane];
      const float4 q1 = grow[lane + 64];
      const float4 q2 = grow[lane + 128];
      const float4 q3 = grow[lane + 192];

      const float4 g0 = *(const float4*)&Lr[co];
      const float4 g1 = *(const float4*)&Lr[co + 256];
      const float4 g2 = *(const float4*)&Lr[co + 512];
      const float4 g3 = *(const float4*)&Lr[co + 768];
      // dmap' (row-shift-invariant part): 10*G - 5*||e||^2
      float4 d0, d1, d2, d3;
      d0.x = 10.f * g0.x - 5.f * es0.x; d0.y = 10.f * g0.y - 5.f * es0.y;
      d0.z = 10.f * g0.z - 5.f * es0.z; d0.w = 10.f * g0.w - 5.f * es0.w;
      d1.x = 10.f * g1.x - 5.f * es1.x; d1.y = 10.f * g1.y - 5.f * es1.y;
      d1.z = 10.f * g1.z - 5.f * es1.z; d1.w = 10.f * g1.w - 5.f * es1.w;
      d2.x = 10.f * g2.x - 5.f * es2.x; d2.y = 10.f * g2.y - 5.f * es2.y;
      d2.z = 10.f * g2.z - 5.f * es2.z; d2.w = 10.f * g2.w - 5.f * es2.w;
      d3.x = 10.f * g3.x - 5.f * es3.x; d3.y = 10.f * g3.y - 5.f * es3.y;
      d3.z = 10.f * g3.z - 5.f * es3.z; d3.w = 10.f * g3.w - 5.f * es3.w;

      // hard argmax (first-index tiebreak)
      float bv = -3.402823466e+38f; int bi = 0;
      AMAX(d0.x, co + 0)   AMAX(d0.y, co + 1)   AMAX(d0.z, co + 2)   AMAX(d0.w, co + 3)
      AMAX(d1.x, co + 256) AMAX(d1.y, co + 257) AMAX(d1.z, co + 258) AMAX(d1.w, co + 259)
      AMAX(d2.x, co + 512) AMAX(d2.y, co + 513) AMAX(d2.z, co + 514) AMAX(d2.w, co + 515)
      AMAX(d3.x, co + 768) AMAX(d3.y, co + 769) AMAX(d3.z, co + 770) AMAX(d3.w, co + 771)
#pragma unroll
      for (int off = 32; off; off >>= 1) {
        const float ov = __shfl_xor(bv, off);
        const int oi = __shfl_xor(bi, off);
        if (ov > bv || (ov == bv && oi < bi)) { bv = ov; bi = oi; }
      }
      if (lane == 0) atomicAdd(&counts[bi], 1);

      // softmax(dmap) -> avg_probs contribution (bv is the row max)
      float4 p0, p1, p2, p3;
      p0.x = __expf(d0.x - bv); p0.y = __expf(d0.y - bv); p0.z = __expf(d0.z - bv); p0.w = __expf(d0.w - bv);
      p1.x = __expf(d1.x - bv); p1.y = __expf(d1.y - bv); p1.z = __expf(d1.z - bv); p1.w = __expf(d1.w - bv);
      p2.x = __expf(d2.x - bv); p2.y = __expf(d2.y - bv); p2.z = __expf(d2.z - bv); p2.w = __expf(d2.w - bv);
      p3.x = __expf(d3.x - bv); p3.y = __expf(d3.y - bv); p3.z = __expf(d3.z - bv); p3.w = __expf(d3.w - bv);
      float ssum = (((p0.x + p0.y) + (p0.z + p0.w)) + ((p1.x + p1.y) + (p1.z + p1.w))) +
                   (((p2.x + p2.y) + (p2.z + p2.w)) + ((p3.x + p3.y) + (p3.z + p3.w)));
#pragma unroll
      for (int off = 32; off; off >>= 1) ssum += __shfl_xor(ssum, off);
      const float inv = 1.0f / ssum;
      cav0.x += p0.x * inv; cav0.y += p0.y * inv; cav0.z += p0.z * inv; cav0.w += p0.w * inv;
      cav1.x += p1.x * inv; cav1.y += p1.y * inv; cav1.z += p1.z * inv; cav1.w += p1.w * inv;
      cav2.x += p2.x * inv; cav2.y += p2.y * inv; cav2.z += p2.z * inv; cav2.w += p2.w * inv;
      cav3.x += p3.x * inv; cav3.y += p3.y * inv; cav3.z += p3.z * inv; cav3.w += p3.w * inv;

      // gumbel path argmax -> quantized index
      float gv = -3.402823466e+38f; int gi = 0;
      GMAX(d0.x + q0.x, co + 0)   GMAX(d0.y + q0.y, co + 1)
      GMAX(d0.z + q0.z, co + 2)   GMAX(d0.w + q0.w, co + 3)
      GMAX(d1.x + q1.x, co + 256) GMAX(d1.y + q1.y, co + 257)
      GMAX(d1.z + q1.z, co + 258) GMAX(d1.w + q1.w, co + 259)
      GMAX(d2.x + q2.x, co + 512) GMAX(d2.y + q2.y, co + 513)
      GMAX(d2.z + q2.z, co + 514) GMAX(d2.w + q2.w, co + 515)
      GMAX(d3.x + q3.x, co + 768) GMAX(d3.y + q3.y, co + 769)
      GMAX(d3.z + q3.z, co + 770) GMAX(d3.w + q3.w, co + 771)
#pragma unroll
      for (int off = 32; off; off >>= 1) {
        const float ov = __shfl_xor(gv, off);
        const int oi = __shfl_xor(gi, off);
        if (ov > gv || (ov == gv && oi < gi)) { gv = ov; gi = oi; }
      }

      // quantized[n] = embedding[gi]; commitment SSE
      const float4* erow = (const float4*)(emb + (size_t)gi * DDIM);
      const float4* xrow = (const float4*)(x + (size_t)n * DDIM);
      float4* orow = (float4*)(out + (size_t)n * DDIM);
#pragma unroll
      for (int c2 = 0; c2 < 2; ++c2) {
        const int f = lane + 64 * c2;
        const float4 ev = erow[f];
        const float4 xv = xrow[f];
        orow[f] = ev;
        const float q0_ = xv.x - ev.x, q1_ = xv.y - ev.y;
        const float q2_ = xv.z - ev.z, q3_ = xv.w - ev.w;
        ss_wave += (q0_ * q0_ + q1_ * q1_) + (q2_ * q2_ + q3_ * q3_);
      }
    }
    __syncthreads();  // Lds reused by next pass
  }

  // one SSE atomic per wave
#pragma unroll
  for (int off = 32; off; off >>= 1) ss_wave += __shfl_xor(ss_wave, off);
  if (lane == 0) atomicAdd(sse, ss_wave);

  // flush avg_probs contributions: LDS accumulate, then one global atom/elem
  atomicAdd(&avg_s[co + 0], cav0.x);   atomicAdd(&avg_s[co + 1], cav0.y);
  atomicAdd(&avg_s[co + 2], cav0.z);   atomicAdd(&avg_s[co + 3], cav0.w);
  atomicAdd(&avg_s[co + 256], cav1.x); atomicAdd(&avg_s[co + 257], cav1.y);
  atomicAdd(&avg_s[co + 258], cav1.z); atomicAdd(&avg_s[co + 259], cav1.w);
  atomicAdd(&avg_s[co + 512], cav2.x); atomicAdd(&avg_s[co + 513], cav2.y);
  atomicAdd(&avg_s[co + 514], cav2.z); atomicAdd(&avg_s[co + 515], cav2.w);
  atomicAdd(&avg_s[co + 768], cav3.x); atomicAdd(&avg_s[co + 769], cav3.y);
  atomicAdd(&avg_s[co + 770], cav3.z); atomicAdd(&avg_s[co + 771], cav3.w);
  __syncthreads();
  atomicAdd(&avg_acc[t], avg_s[t]);
  atomicAdd(&avg_acc[t + 512], avg_s[t + 512]);
}

// ---------------------------------------------------------------------------
__global__ __launch_bounds__(1024)
void finalize(const float* __restrict__ avg_acc, const int* __restrict__ counts,
              const float* __restrict__ sse, float* __restrict__ out) {
  __shared__ float red[32];
  const int t = threadIdx.x;
  const float invN = 1.f / 32768.f;
  const float p = (float)counts[t] * invN;
  float a = p * log2f(p + 1e-10f);
  const float q = avg_acc[t] * invN;
  float b = q * log2f(q + 1e-10f);
#pragma unroll
  for (int off = 32; off; off >>= 1) {
    a += __shfl_xor(a, off);
    b += __shfl_xor(b, off);
  }
  const int wv = t >> 6, ln = t & 63;
  if (ln == 0) { red[wv] = a; red[wv + 16] = b; }
  __syncthreads();
  if (t == 0) {
    float sa = 0.f, sb = 0.f;
#pragma unroll
    for (int i = 0; i < 16; ++i) { sa += red[i]; sb += red[i + 16]; }
    out[QOFF + 0] = -sa;                                // code_perplexity
    out[QOFF + 1] = -sb;                                // prob_perplexity
    out[QOFF + 2] = sse[0] * (1.f / (32768.f * 512.f)); // commitment_loss
  }
}

// ---------------------------------------------------------------------------
extern "C" void kernel_launch(void* const* d_in, const int* in_sizes, int n_in,
                              void* d_out, int out_size, void* d_ws,
                              size_t ws_size, hipStream_t stream) {
  const float* x = (const float*)d_in[0];
  const float* e = (const float*)d_in[1];
  const float* g = (const float*)d_in[2];
  float* out = (float*)d_out;
  float* ws = (float*)d_ws;
  // ws layout (floats): [0,1024) esq | [1024,2048) avg_acc |
  //   [2048,3072) counts(int) | [3072] sse | [4096, +512K) Ehi/Elo fragments
  float* esq = ws;
  float* avg_acc = ws + 1024;
  int* counts = (int*)(ws + 2048);
  float* sse = ws + 3072;
  _Float16* ehi = (_Float16*)(ws + 4096);        // 1024*512 halves = 1 MB
  _Float16* elo = ehi + (size_t)MDIM * DDIM;     // 1 MB

  // zero the cross-block accumulators (ws is poisoned 0xAA, not re-zeroed)
  hipMemsetAsync(avg_acc, 0, (1024 + 1024 + 1) * sizeof(float), stream);

  e_to_frag<<<256, 256, 0, stream>>>(e, ehi, elo);
  esq_kernel<<<256, 256, 0, stream>>>(e, esq);
  vq_main<<<NTOT / BN, 512, 0, stream>>>(x, e, ehi, elo, g, esq, out, avg_acc,
                                         counts, sse);
  finalize<<<1, 1024, 0, stream>>>(avg_acc, counts, sse, out);
}

// Round 5
// 243.430 us; speedup vs baseline: 2.0866x; 1.8136x over previous
//
#include <hip/hip_runtime.h>
#include <math.h>

// Problem constants (GumbelVectorQuantizer): B=16,T=2048,D=512,M=1024
#define NTOT 32768   // B*T
#define DDIM 512
#define MDIM 1024
#define QOFF 16777216  // quantized element count (output scalars follow)

typedef _Float16 f16x8 __attribute__((ext_vector_type(8)));
typedef float    f32x4 __attribute__((ext_vector_type(4)));

// async global->LDS: per-LANE global src pointer, wave-uniform LDS dest base
// (HW adds lane*16 to the LDS address).
__device__ __forceinline__ void gload_lds16(const void* g, void* l) {
  __builtin_amdgcn_global_load_lds(
      (const __attribute__((address_space(1))) void*)g,
      (__attribute__((address_space(3))) void*)l, 16, 0, 0);
}

// ---------------------------------------------------------------------------
// esq[m] = sum_d e[m][d]^2
__global__ __launch_bounds__(256) void esq_kernel(const float* __restrict__ e,
                                                  float* __restrict__ esq) {
  const int w = threadIdx.x >> 6, lane = threadIdx.x & 63;
  const int m = blockIdx.x * 4 + w;
  const float4* row = (const float4*)(e + (size_t)m * DDIM);
  const float4 a = row[lane * 2];
  const float4 b = row[lane * 2 + 1];
  float s = ((a.x * a.x + a.y * a.y) + (a.z * a.z + a.w * a.w)) +
            ((b.x * b.x + b.y * b.y) + (b.z * b.z + b.w * b.w));
#pragma unroll
  for (int off = 32; off; off >>= 1) s += __shfl_xor(s, off);
  if (lane == 0) esq[m] = s;
}

// ---------------------------------------------------------------------------
// Pre-swizzle E into MFMA B-fragment order, fp16 hi/lo split.
// Flat order: [mt(8)][ks(16)][ctg(8)][lane(64)][8 halves] so one (mt,ks)
// slab is 8 KB contiguous (linear global_load_lds staging).
// Lane l elem j holds B[k=ks*32+(l>>4)*8+j][col=mt*128+ctg*16+(l&15)] = E[col][k].
__global__ __launch_bounds__(256) void e_to_frag(const float* __restrict__ e,
                                                 _Float16* __restrict__ hi,
                                                 _Float16* __restrict__ lo) {
  const int tid = blockIdx.x * 256 + threadIdx.x;   // 65536 threads
  const int lane = tid & 63;
  const int F = tid >> 6;            // F = mt*128 + ks*8 + ctg
  const int mt = F >> 7;
  const int ks = (F >> 3) & 15;
  const int ctg = F & 7;
  const int m = mt * 128 + ctg * 16 + (lane & 15);
  const int k0 = ks * 32 + (lane >> 4) * 8;
  const float* src = e + (size_t)m * DDIM + k0;
  const float4 a = *(const float4*)src;
  const float4 b = *(const float4*)(src + 4);
  f16x8 vh, vl;
  vh[0] = (_Float16)a.x; vl[0] = (_Float16)(a.x - (float)vh[0]);
  vh[1] = (_Float16)a.y; vl[1] = (_Float16)(a.y - (float)vh[1]);
  vh[2] = (_Float16)a.z; vl[2] = (_Float16)(a.z - (float)vh[2]);
  vh[3] = (_Float16)a.w; vl[3] = (_Float16)(a.w - (float)vh[3]);
  vh[4] = (_Float16)b.x; vl[4] = (_Float16)(b.x - (float)vh[4]);
  vh[5] = (_Float16)b.y; vl[5] = (_Float16)(b.y - (float)vh[5]);
  vh[6] = (_Float16)b.z; vl[6] = (_Float16)(b.z - (float)vh[6]);
  vh[7] = (_Float16)b.w; vl[7] = (_Float16)(b.w - (float)vh[7]);
  *(f16x8*)(hi + (size_t)tid * 8) = vh;
  *(f16x8*)(lo + (size_t)tid * 8) = vl;
}

// ---------------------------------------------------------------------------
// GEMM: dmap' = 10 * X.E^T - 5*||e||^2  via fp16 hi/lo split (3 MFMA/term-set)
// m97 structure: 128x128 tile, BK=32, 4 waves, global_load_lds double buffer,
// one barrier pair per K-step. A-slab XOR-swizzled (b ^= (row&7)<<4) via
// pre-swizzled global source; B-slabs are pre-fragmented (linear).
#define CVT1(RT, J, V)                                                         \
  Ah[RT][J] = (_Float16)(V);                                                   \
  Al[RT][J] = (_Float16)((V) - (float)Ah[RT][J]);
#define CVT8(RT, A0, A1)                                                       \
  CVT1(RT, 0, A0[0]) CVT1(RT, 1, A0[1]) CVT1(RT, 2, A0[2]) CVT1(RT, 3, A0[3]) \
  CVT1(RT, 4, A1[0]) CVT1(RT, 5, A1[1]) CVT1(RT, 6, A1[2]) CVT1(RT, 7, A1[3])

#define STAGE(AsP, BhP, BlP, KS)                                               \
  {                                                                            \
    _Pragma("unroll") for (int i_ = 0; i_ < 4; ++i_) {                         \
      const int row_ = (w * 4 + i_) * 8 + (lane >> 3);                         \
      const int cf_ = ((lane & 7) ^ (row_ & 7)) * 4;                           \
      gload_lds16(x + (size_t)(n0 + row_) * DDIM + (KS) * 32 + cf_,            \
                  (AsP) + (w * 4 + i_) * 1024);                                \
    }                                                                          \
    _Pragma("unroll") for (int i_ = 0; i_ < 2; ++i_) {                         \
      const size_t so_ =                                                       \
          (size_t)(mt * 16 + (KS)) * 8192 + (w * 2 + i_) * 1024 + lane * 16;   \
      gload_lds16((const char*)ehi + so_, (BhP) + (w * 2 + i_) * 1024);        \
      gload_lds16((const char*)elo + so_, (BlP) + (w * 2 + i_) * 1024);        \
    }                                                                          \
  }

#define COMPUTE(AsP, BhP, BlP)                                                 \
  {                                                                            \
    f16x8 Bhf[8], Blf[8];                                                      \
    _Pragma("unroll") for (int c_ = 0; c_ < 8; ++c_) {                         \
      Bhf[c_] = *(const f16x8*)((BhP) + c_ * 1024 + lane * 16);                \
      Blf[c_] = *(const f16x8*)((BlP) + c_ * 1024 + lane * 16);                \
    }                                                                          \
    f16x8 Ah[2], Al[2];                                                        \
    _Pragma("unroll") for (int rt_ = 0; rt_ < 2; ++rt_) {                      \
      const int row_ = w * 32 + rt_ * 16 + l15;                                \
      const int sw_ = (row_ & 7) << 4;                                         \
      const char* rb_ = (AsP) + row_ * 128;                                    \
      const f32x4 a0_ = *(const f32x4*)(rb_ + ((lg * 32) ^ sw_));              \
      const f32x4 a1_ = *(const f32x4*)(rb_ + ((lg * 32 + 16) ^ sw_));         \
      CVT8(rt_, a0_, a1_)                                                      \
    }                                                                          \
    _Pragma("unroll") for (int c_ = 0; c_ < 8; ++c_)                           \
        _Pragma("unroll") for (int rt_ = 0; rt_ < 2; ++rt_)                    \
            acc[rt_][c_] = __builtin_amdgcn_mfma_f32_16x16x32_f16(             \
                Ah[rt_], Bhf[c_], acc[rt_][c_], 0, 0, 0);                      \
    _Pragma("unroll") for (int c_ = 0; c_ < 8; ++c_)                           \
        _Pragma("unroll") for (int rt_ = 0; rt_ < 2; ++rt_)                    \
            acc[rt_][c_] = __builtin_amdgcn_mfma_f32_16x16x32_f16(             \
                Al[rt_], Bhf[c_], acc[rt_][c_], 0, 0, 0);                      \
    _Pragma("unroll") for (int c_ = 0; c_ < 8; ++c_)                           \
        _Pragma("unroll") for (int rt_ = 0; rt_ < 2; ++rt_)                    \
            acc[rt_][c_] = __builtin_amdgcn_mfma_f32_16x16x32_f16(             \
                Ah[rt_], Blf[c_], acc[rt_][c_], 0, 0, 0);                      \
  }

__global__ __launch_bounds__(256, 2)
void gemm_dmap(const float* __restrict__ x, const _Float16* __restrict__ ehi,
               const _Float16* __restrict__ elo, const float* __restrict__ esq,
               float* __restrict__ dmap) {
  __shared__ __align__(16) char smem[66048];
  char* const AsA = smem;              // A slab fp32 [128][32] = 16 KB
  char* const AsB = smem + 16384;
  char* const BhA = smem + 32768;      // B hi frag slab 8 KB
  char* const BhB = smem + 40960;
  char* const BlA = smem + 49152;      // B lo frag slab 8 KB
  char* const BlB = smem + 57344;
  float* const esqt = (float*)(smem + 65536);

  const int t = threadIdx.x;
  const int w = t >> 6;
  const int lane = t & 63;
  const int l15 = lane & 15;
  const int lg = lane >> 4;
  const int mt = blockIdx.x & 7;        // 8 column tiles (consecutive bids
  const int nt = blockIdx.x >> 3;       //  share the same X row-panel in L2)
  const int n0 = nt * 128;              // chunk-local row base

  if (t < 128) esqt[t] = esq[mt * 128 + t];

  f32x4 acc[2][8];
#pragma unroll
  for (int rt = 0; rt < 2; ++rt)
#pragma unroll
    for (int c = 0; c < 8; ++c) acc[rt][c] = (f32x4){0.f, 0.f, 0.f, 0.f};

  STAGE(AsA, BhA, BlA, 0)
  __syncthreads();

  for (int kk = 0; kk < 8; ++kk) {
    const int ks = kk * 2;
    STAGE(AsB, BhB, BlB, ks + 1)
    COMPUTE(AsA, BhA, BlA)
    __syncthreads();
    if (ks + 2 < 16) STAGE(AsA, BhA, BlA, ks + 2)
    COMPUTE(AsB, BhB, BlB)
    __syncthreads();
  }

  // epilogue: dmap' = 10*acc - 5*esq, strided 64B-segment stores
#pragma unroll
  for (int rt = 0; rt < 2; ++rt)
#pragma unroll
    for (int ct = 0; ct < 8; ++ct) {
      const float e5 = 5.f * esqt[ct * 16 + l15];
      float* dr = dmap + (size_t)(n0 + w * 32 + rt * 16 + lg * 4) * 1024 +
                  mt * 128 + ct * 16 + l15;
#pragma unroll
      for (int rg = 0; rg < 4; ++rg)
        dr[(size_t)rg * 1024] = 10.f * acc[rt][ct][rg] - e5;
    }
}

// ---------------------------------------------------------------------------
#define AMAX(V, MM)                                                            \
  { const float v_ = (V); const int m_ = (MM);                                 \
    if (v_ > bv || (v_ == bv && m_ < bi)) { bv = v_; bi = m_; } }
#define GMAX(V, MM)                                                            \
  { const float v_ = (V); const int m_ = (MM);                                 \
    if (v_ > gv || (v_ == gv && m_ < gi)) { gv = v_; gi = m_; } }

// Streaming epilogue: per-row argmax -> counts, softmax -> avg_probs,
// gumbel argmax -> gather + SSE.  High occupancy (4 KB LDS, light VGPR).
__global__ __launch_bounds__(256)
void epi(const float* __restrict__ x, const float* __restrict__ emb,
         const float* __restrict__ dmap, const float* __restrict__ gum,
         float* __restrict__ out, float* __restrict__ avg_acc,
         int* __restrict__ counts, float* __restrict__ sse) {
  __shared__ float avg_s[MDIM];
  const int t = threadIdx.x;
  const int w = t >> 6;
  const int lane = t & 63;
  const int co = lane << 2;
  avg_s[t] = 0.f; avg_s[t + 256] = 0.f; avg_s[t + 512] = 0.f; avg_s[t + 768] = 0.f;
  __syncthreads();

  float4 cav0 = make_float4(0.f, 0.f, 0.f, 0.f);
  float4 cav1 = make_float4(0.f, 0.f, 0.f, 0.f);
  float4 cav2 = make_float4(0.f, 0.f, 0.f, 0.f);
  float4 cav3 = make_float4(0.f, 0.f, 0.f, 0.f);
  float ss_wave = 0.f;

  for (int i = 0; i < 8; ++i) {
    const int n = blockIdx.x * 32 + w * 8 + i;  // chunk-local row
    const float* Dr = dmap + (size_t)n * MDIM;
    const float4* grow = (const float4*)(gum + (size_t)n * MDIM);
    // issue gumbel loads early; latency hides under argmax/softmax
    const float4 q0 = grow[lane];
    const float4 q1 = grow[lane + 64];
    const float4 q2 = grow[lane + 128];
    const float4 q3 = grow[lane + 192];
    const float4 d0 = *(const float4*)&Dr[co];
    const float4 d1 = *(const float4*)&Dr[co + 256];
    const float4 d2 = *(const float4*)&Dr[co + 512];
    const float4 d3 = *(const float4*)&Dr[co + 768];

    // hard argmax (first-index tiebreak)
    float bv = -3.402823466e+38f; int bi = 0;
    AMAX(d0.x, co + 0)   AMAX(d0.y, co + 1)   AMAX(d0.z, co + 2)   AMAX(d0.w, co + 3)
    AMAX(d1.x, co + 256) AMAX(d1.y, co + 257) AMAX(d1.z, co + 258) AMAX(d1.w, co + 259)
    AMAX(d2.x, co + 512) AMAX(d2.y, co + 513) AMAX(d2.z, co + 514) AMAX(d2.w, co + 515)
    AMAX(d3.x, co + 768) AMAX(d3.y, co + 769) AMAX(d3.z, co + 770) AMAX(d3.w, co + 771)
#pragma unroll
    for (int off = 32; off; off >>= 1) {
      const float ov = __shfl_xor(bv, off);
      const int oi = __shfl_xor(bi, off);
      if (ov > bv || (ov == bv && oi < bi)) { bv = ov; bi = oi; }
    }
    if (lane == 0) atomicAdd(&counts[bi], 1);

    // softmax(dmap') -> avg_probs contribution (bv is the row max)
    float4 p0, p1, p2, p3;
    p0.x = __expf(d0.x - bv); p0.y = __expf(d0.y - bv); p0.z = __expf(d0.z - bv); p0.w = __expf(d0.w - bv);
    p1.x = __expf(d1.x - bv); p1.y = __expf(d1.y - bv); p1.z = __expf(d1.z - bv); p1.w = __expf(d1.w - bv);
    p2.x = __expf(d2.x - bv); p2.y = __expf(d2.y - bv); p2.z = __expf(d2.z - bv); p2.w = __expf(d2.w - bv);
    p3.x = __expf(d3.x - bv); p3.y = __expf(d3.y - bv); p3.z = __expf(d3.z - bv); p3.w = __expf(d3.w - bv);
    float ssum = (((p0.x + p0.y) + (p0.z + p0.w)) + ((p1.x + p1.y) + (p1.z + p1.w))) +
                 (((p2.x + p2.y) + (p2.z + p2.w)) + ((p3.x + p3.y) + (p3.z + p3.w)));
#pragma unroll
    for (int off = 32; off; off >>= 1) ssum += __shfl_xor(ssum, off);
    const float inv = 1.0f / ssum;
    cav0.x += p0.x * inv; cav0.y += p0.y * inv; cav0.z += p0.z * inv; cav0.w += p0.w * inv;
    cav1.x += p1.x * inv; cav1.y += p1.y * inv; cav1.z += p1.z * inv; cav1.w += p1.w * inv;
    cav2.x += p2.x * inv; cav2.y += p2.y * inv; cav2.z += p2.z * inv; cav2.w += p2.w * inv;
    cav3.x += p3.x * inv; cav3.y += p3.y * inv; cav3.z += p3.z * inv; cav3.w += p3.w * inv;

    // gumbel path argmax -> quantized index
    float gv = -3.402823466e+38f; int gi = 0;
    GMAX(d0.x + q0.x, co + 0)   GMAX(d0.y + q0.y, co + 1)
    GMAX(d0.z + q0.z, co + 2)   GMAX(d0.w + q0.w, co + 3)
    GMAX(d1.x + q1.x, co + 256) GMAX(d1.y + q1.y, co + 257)
    GMAX(d1.z + q1.z, co + 258) GMAX(d1.w + q1.w, co + 259)
    GMAX(d2.x + q2.x, co + 512) GMAX(d2.y + q2.y, co + 513)
    GMAX(d2.z + q2.z, co + 514) GMAX(d2.w + q2.w, co + 515)
    GMAX(d3.x + q3.x, co + 768) GMAX(d3.y + q3.y, co + 769)
    GMAX(d3.z + q3.z, co + 770) GMAX(d3.w + q3.w, co + 771)
#pragma unroll
    for (int off = 32; off; off >>= 1) {
      const float ov = __shfl_xor(gv, off);
      const int oi = __shfl_xor(gi, off);
      if (ov > gv || (ov == gv && oi < gi)) { gv = ov; gi = oi; }
    }

    // quantized[n] = embedding[gi]; commitment SSE
    const float4* erow = (const float4*)(emb + (size_t)gi * DDIM);
    const float4* xrow = (const float4*)(x + (size_t)n * DDIM);
    float4* orow = (float4*)(out + (size_t)n * DDIM);
#pragma unroll
    for (int c2 = 0; c2 < 2; ++c2) {
      const int f = lane + 64 * c2;
      const float4 ev = erow[f];
      const float4 xv = xrow[f];
      orow[f] = ev;
      const float q0_ = xv.x - ev.x, q1_ = xv.y - ev.y;
      const float q2_ = xv.z - ev.z, q3_ = xv.w - ev.w;
      ss_wave += (q0_ * q0_ + q1_ * q1_) + (q2_ * q2_ + q3_ * q3_);
    }
  }

#pragma unroll
  for (int off = 32; off; off >>= 1) ss_wave += __shfl_xor(ss_wave, off);
  if (lane == 0) atomicAdd(sse, ss_wave);

  atomicAdd(&avg_s[co + 0], cav0.x);   atomicAdd(&avg_s[co + 1], cav0.y);
  atomicAdd(&avg_s[co + 2], cav0.z);   atomicAdd(&avg_s[co + 3], cav0.w);
  atomicAdd(&avg_s[co + 256], cav1.x); atomicAdd(&avg_s[co + 257], cav1.y);
  atomicAdd(&avg_s[co + 258], cav1.z); atomicAdd(&avg_s[co + 259], cav1.w);
  atomicAdd(&avg_s[co + 512], cav2.x); atomicAdd(&avg_s[co + 513], cav2.y);
  atomicAdd(&avg_s[co + 514], cav2.z); atomicAdd(&avg_s[co + 515], cav2.w);
  atomicAdd(&avg_s[co + 768], cav3.x); atomicAdd(&avg_s[co + 769], cav3.y);
  atomicAdd(&avg_s[co + 770], cav3.z); atomicAdd(&avg_s[co + 771], cav3.w);
  __syncthreads();
  atomicAdd(&avg_acc[t], avg_s[t]);
  atomicAdd(&avg_acc[t + 256], avg_s[t + 256]);
  atomicAdd(&avg_acc[t + 512], avg_s[t + 512]);
  atomicAdd(&avg_acc[t + 768], avg_s[t + 768]);
}

// ---------------------------------------------------------------------------
__global__ __launch_bounds__(1024)
void finalize(const float* __restrict__ avg_acc, const int* __restrict__ counts,
              const float* __restrict__ sse, float* __restrict__ out) {
  __shared__ float red[32];
  const int t = threadIdx.x;
  const float invN = 1.f / 32768.f;
  const float p = (float)counts[t] * invN;
  float a = p * log2f(p + 1e-10f);
  const float q = avg_acc[t] * invN;
  float b = q * log2f(q + 1e-10f);
#pragma unroll
  for (int off = 32; off; off >>= 1) {
    a += __shfl_xor(a, off);
    b += __shfl_xor(b, off);
  }
  const int wv = t >> 6, ln = t & 63;
  if (ln == 0) { red[wv] = a; red[wv + 16] = b; }
  __syncthreads();
  if (t == 0) {
    float sa = 0.f, sb = 0.f;
#pragma unroll
    for (int i = 0; i < 16; ++i) { sa += red[i]; sb += red[i + 16]; }
    out[QOFF + 0] = -sa;                                // code_perplexity
    out[QOFF + 1] = -sb;                                // prob_perplexity
    out[QOFF + 2] = sse[0] * (1.f / (32768.f * 512.f)); // commitment_loss
  }
}

// ---------------------------------------------------------------------------
extern "C" void kernel_launch(void* const* d_in, const int* in_sizes, int n_in,
                              void* d_out, int out_size, void* d_ws,
                              size_t ws_size, hipStream_t stream) {
  const float* x = (const float*)d_in[0];
  const float* e = (const float*)d_in[1];
  const float* g = (const float*)d_in[2];
  float* out = (float*)d_out;
  char* wsb = (char*)d_ws;
  // ws layout (bytes): esq@0 (4K) | avg_acc@4K (4K) | counts@8K (4K) |
  //   sse@12K | efrag hi@16K (1M) | efrag lo@16K+1M (1M) | dmap@16K+2M
  float* esq = (float*)wsb;
  float* avg_acc = (float*)(wsb + 4096);
  int* counts = (int*)(wsb + 8192);
  float* sse = (float*)(wsb + 12288);
  _Float16* ehi = (_Float16*)(wsb + 16384);
  _Float16* elo = (_Float16*)(wsb + 16384 + 1048576);
  float* dmap = (float*)(wsb + 16384 + 2097152);

  // chunk rows so dmap (4 KB/row fp32) fits in the remaining workspace
  const size_t cap = (ws_size > 2113536) ? ws_size - 2113536 : 0;
  long long cr = (long long)(cap / 4096);
  cr = (cr / 128) * 128;
  if (cr > NTOT) cr = NTOT;
  if (cr < 128) cr = 128;
  const int chunk_rows = (int)cr;

  hipMemsetAsync(wsb + 4096, 0, 8192 + 16, stream);  // avg_acc, counts, sse

  e_to_frag<<<256, 256, 0, stream>>>(e, ehi, elo);
  esq_kernel<<<256, 256, 0, stream>>>(e, esq);

  for (int n0 = 0; n0 < NTOT; n0 += chunk_rows) {
    const int rows = (NTOT - n0 < chunk_rows) ? (NTOT - n0) : chunk_rows;
    gemm_dmap<<<8 * (rows / 128), 256, 0, stream>>>(
        x + (size_t)n0 * DDIM, ehi, elo, esq, dmap);
    epi<<<rows / 32, 256, 0, stream>>>(
        x + (size_t)n0 * DDIM, e, dmap, g + (size_t)n0 * MDIM,
        out + (size_t)n0 * DDIM, avg_acc, counts, sse);
  }
  finalize<<<1, 1024, 0, stream>>>(avg_acc, counts, sse, out);
}